// Round 3
// baseline (479.835 us; speedup 1.0000x reference)
//
#include <hip/hip_runtime.h>
#include <hip/hip_bf16.h>
#include <stdint.h>

// RecNN: B=2048, L=256 leaves, F=64, H=128.
// One workgroup (512 thr, 8 waves) per 8 batch elems. Hybrid subtree-BFS
// (16 leaves level-synchronous, M up to 128) + DFS over 16 subtree roots.
// Weights live in registers as MFMA B-fragments; activations in LDS.
// launch_bounds(512,1): 256-VGPR budget — (512,2) capped at 128 and spilled
// ~370 MB/dispatch of scratch traffic (round-2 post-mortem).

#define B_TOT 2048
#define LL    256
#define FF    64
#define HH    128
#define LF    (LL*FF)
#define BC    8
#define NTHR  512
#define SUB   16
#define NSUB  16

typedef __bf16 v8bf __attribute__((ext_vector_type(8)));
typedef float  v4f  __attribute__((ext_vector_type(4)));

// ---- LDS layout (all 2D buffers use 256-byte rows, XOR-swizzled) ----
#define D0_OFF    0        // [128][64] f32   32768  (x / data2 / data-scratch)
#define DB_OFF    32768    // [64][64]  f32   16384  (data1 / data3 / data4@16)
#define HA_OFF    49152    // [128][128]bf16  32768  (h0 / h2)
#define HB_OFF    81920    // [64][128] bf16  16384  (h1 / h3 / z2)
#define U_OFF     98304    // [64][128] bf16  16384  (u / z1)
#define HCUR_OFF  114688   // [16][128] bf16  4096   (subtree/merge root h)
#define DCUR_OFF  118784   // [8][64]   f32   2048   (root data)
#define HSTK_OFF  120832   // 4 x 4096        16384
#define DSTK_OFF  137216   // 4 x 2048        8192
#define BIAS_OFF  145408   // 4 x 512         2048
#define LDS_BYTES 147456

__device__ __forceinline__ uint32_t swz(uint32_t row, uint32_t b){
    return (row*256u + b) ^ ((row & 7u) << 4);
}
__device__ __forceinline__ v4f mfma16(v8bf a, v8bf b, v4f c){
    return __builtin_amdgcn_mfma_f32_16x16x32_bf16(a, b, c, 0, 0, 0);
}

// B-fragment: lane holds col n0+(l&15), k = k0 + 8*(l>>4) + j. W row-major [K][128] f32.
__device__ __forceinline__ v8bf ldW(const float* __restrict__ W, int k0, int n0){
    uint32_t lane = threadIdx.x & 63u;
    int n = n0 + (int)(lane & 15u);
    int k = k0 + (int)((lane >> 4) << 3);
    v8bf r;
    #pragma unroll
    for (int j = 0; j < 8; ++j) r[j] = (__bf16)W[(k + j)*HH + n];
    return r;
}

// A-fragment from 16-row bf16 buffer, row = lane&15 (merge/head GEMMs)
__device__ __forceinline__ v8bf ldH(const char* buf, uint32_t kf){
    uint32_t lane = threadIdx.x & 63u;
    uint32_t kb = (kf*32u + ((lane >> 4) << 3)) * 2u;
    return *reinterpret_cast<const v8bf*>(buf + swz(lane & 15u, kb));
}

// A-fragment for subtree nl GEMM (node-major rows): tile row r -> node 2mt+(r>=8),
// children rows 32mt+16*(r>=8)+8*sec+(r&7) in hprev; u row 16mt+r.
__device__ __forceinline__ v8bf ldA_nl(const char* hprev, const char* ub, uint32_t mt, uint32_t kf){
    uint32_t lane = threadIdx.x & 63u, r = lane & 15u;
    uint32_t kb = ((kf & 3u)*32u + ((lane >> 4) << 3)) * 2u;
    uint32_t sec = kf >> 2;
    if (sec < 2u){
        uint32_t row = mt*32u + ((r >> 3) << 4) + sec*8u + (r & 7u);
        return *reinterpret_cast<const v8bf*>(hprev + swz(row, kb));
    }
    return *reinterpret_cast<const v8bf*>(ub + swz(mt*16u + r, kb));
}

// A-fragment from f32 data buffer (K=64), on-the-fly bf16 convert; rows >= realrows -> 0
__device__ __forceinline__ v8bf ldA_f32(const char* dbuf, uint32_t rowbase, uint32_t mt,
                                        uint32_t kf, uint32_t realrows){
    uint32_t lane = threadIdx.x & 63u, r = lane & 15u;
    uint32_t row = mt*16u + r;
    v8bf o;
    if (row >= realrows){
        #pragma unroll
        for (int j = 0; j < 8; ++j) o[j] = (__bf16)0.0f;
        return o;
    }
    uint32_t kb = kf*128u + ((lane >> 4) << 5);
    v4f lo = *reinterpret_cast<const v4f*>(dbuf + swz(rowbase + row, kb));
    v4f hi = *reinterpret_cast<const v4f*>(dbuf + swz(rowbase + row, kb + 16u));
    #pragma unroll
    for (int j = 0; j < 4; ++j){ o[j] = (__bf16)lo[j]; o[j+4] = (__bf16)hi[j]; }
    return o;
}

// Epilogue: D elem r -> [row0+(l>>4)*4+r][16*nt+(l&15)]; relu(acc+bias) -> bf16 swz LDS
__device__ __forceinline__ void epi(char* dst, uint32_t row0, v4f acc, int nt, const float* bias){
    uint32_t lane = threadIdx.x & 63u;
    uint32_t col = (uint32_t)nt*16u + (lane & 15u);
    float bv = bias[col];
    uint32_t r0 = row0 + ((lane >> 4) << 2);
    #pragma unroll
    for (int r = 0; r < 4; ++r){
        float v = fmaxf(acc[r] + bv, 0.f);
        *reinterpret_cast<__bf16*>(dst + swz(r0 + r, col*2u)) = (__bf16)v;
    }
}

// relu(data @ Wleaf + bias) for MTN 16-row tiles starting at tile mtB
template<int MTN>
__device__ __forceinline__ void gemm_data(const char* dbuf, uint32_t rowbase, uint32_t realrows,
                                          char* dst, uint32_t mtB, const v8bf (&wlf)[2][2],
                                          int nt0, const float* bias){
    v4f acc[MTN][2];
    #pragma unroll
    for (int i = 0; i < MTN; ++i){ acc[i][0] = (v4f){0,0,0,0}; acc[i][1] = (v4f){0,0,0,0}; }
    #pragma unroll
    for (uint32_t kf = 0; kf < 2; ++kf){
        v8bf a[MTN];
        #pragma unroll
        for (int i = 0; i < MTN; ++i) a[i] = ldA_f32(dbuf, rowbase, mtB + i, kf, realrows);
        #pragma unroll
        for (int i = 0; i < MTN; ++i){
            acc[i][0] = mfma16(a[i], wlf[kf][0], acc[i][0]);
            acc[i][1] = mfma16(a[i], wlf[kf][1], acc[i][1]);
        }
    }
    #pragma unroll
    for (int i = 0; i < MTN; ++i){
        epi(dst, (mtB + i)*16u, acc[i][0], nt0,     bias);
        epi(dst, (mtB + i)*16u, acc[i][1], nt0 + 1, bias);
    }
}

// relu([h_even|h_odd|u] @ Wnl + bias), node-major
template<int MTN>
__device__ __forceinline__ void gemm_nl(const char* hprev, const char* ub, char* dst, uint32_t mtB,
                                        const v8bf (&wnl)[12][2], int nt0, const float* bias){
    v4f acc[MTN][2];
    #pragma unroll
    for (int i = 0; i < MTN; ++i){ acc[i][0] = (v4f){0,0,0,0}; acc[i][1] = (v4f){0,0,0,0}; }
    #pragma unroll
    for (uint32_t kf = 0; kf < 12; ++kf){
        v8bf a[MTN];
        #pragma unroll
        for (int i = 0; i < MTN; ++i) a[i] = ldA_nl(hprev, ub, mtB + i, kf);
        #pragma unroll
        for (int i = 0; i < MTN; ++i){
            acc[i][0] = mfma16(a[i], wnl[kf][0], acc[i][0]);
            acc[i][1] = mfma16(a[i], wnl[kf][1], acc[i][1]);
        }
    }
    #pragma unroll
    for (int i = 0; i < MTN; ++i){
        epi(dst, (mtB + i)*16u, acc[i][0], nt0,     bias);
        epi(dst, (mtB + i)*16u, acc[i][1], nt0 + 1, bias);
    }
}

// data_next[n*8+b] = data[16n+b] + data[16n+8+b], elementwise over swizzled f32 rows
__device__ __forceinline__ void sumpair(char* dstbuf, uint32_t dRow0, const char* srcbuf,
                                        uint32_t sRow0, int nrows){
    int total = nrows * 64;
    for (int idx = threadIdx.x; idx < total; idx += NTHR){
        uint32_t row = (uint32_t)(idx >> 6), f = (uint32_t)(idx & 63);
        uint32_t n = row >> 3, b = row & 7u;
        float x0 = *reinterpret_cast<const float*>(srcbuf + swz(sRow0 + n*16u + b,      f*4u));
        float x1 = *reinterpret_cast<const float*>(srcbuf + swz(sRow0 + n*16u + 8u + b, f*4u));
        *reinterpret_cast<float*>(dstbuf + swz(dRow0 + row, f*4u)) = x0 + x1;
    }
}

__global__ __launch_bounds__(NTHR, 1)
void recnn_kernel(const float* __restrict__ Xg,
                  const float* __restrict__ Wleaf, const float* __restrict__ bleaf,
                  const float* __restrict__ Wnl,   const float* __restrict__ bnl,
                  const float* __restrict__ W1g,   const float* __restrict__ b1g,
                  const float* __restrict__ W2g,   const float* __restrict__ b2g,
                  const float* __restrict__ W3g,   const float* __restrict__ b3g,
                  float* __restrict__ Yg)
{
    __shared__ __align__(16) char lds[LDS_BYTES];
    const int t    = threadIdx.x;
    const int wave = t >> 6;
    const int wn   = wave & 3, wm = wave >> 2;
    const int base = blockIdx.x * BC;

    char*  D0   = lds + D0_OFF;
    char*  DBf  = lds + DB_OFF;
    char*  HA   = lds + HA_OFF;
    char*  HB   = lds + HB_OFF;
    char*  Ub   = lds + U_OFF;
    char*  HCUR = lds + HCUR_OFF;
    char*  DCUR = lds + DCUR_OFF;
    char*  HSTK = lds + HSTK_OFF;
    char*  DSTK = lds + DSTK_OFF;
    float* BL   = (float*)(lds + BIAS_OFF);
    float* BN   = BL + 128;
    float* B1L  = BL + 256;
    float* B2L  = BL + 384;

    if (t < 128){
        BL[t]  = bleaf[t];
        BN[t]  = bnl[t];
        B1L[t] = b1g[t];
        B2L[t] = b2g[t];
    }

    // Persistent weight fragments: wave column-group wn owns cols [32wn, 32wn+32)
    const int n0  = wn << 5;
    const int nt0 = wn * 2;
    v8bf wlf[2][2], wnl[12][2];
    #pragma unroll
    for (int kf = 0; kf < 2; ++kf){
        wlf[kf][0] = ldW(Wleaf, kf*32, n0);
        wlf[kf][1] = ldW(Wleaf, kf*32, n0 + 16);
    }
    #pragma unroll
    for (int kf = 0; kf < 12; ++kf){
        wnl[kf][0] = ldW(Wnl, kf*32, n0);
        wnl[kf][1] = ldW(Wnl, kf*32, n0 + 16);
    }

    int sp = 0;
    for (int s = 0; s < NSUB; ++s){
        // push previous root, stage x for this subtree -> D0 (f32 swz)
        if (s > 0){
            ((uint2*)(HSTK + sp*4096))[t]     = ((const uint2*)HCUR)[t];
            ((uint32_t*)(DSTK + sp*2048))[t]  = ((const uint32_t*)DCUR)[t];
            ++sp;
        }
        #pragma unroll
        for (int k = 0; k < 4; ++k){
            int idx = t + k*NTHR;                       // 0..2047
            uint32_t row = (uint32_t)(idx >> 4), q = (uint32_t)(idx & 15);
            int li = (int)(row >> 3), bb = (int)(row & 7u);
            v4f x4 = *reinterpret_cast<const v4f*>(
                Xg + (size_t)(base + bb)*LF + (size_t)(s*SUB + li)*FF + q*4);
            *reinterpret_cast<v4f*>(D0 + swz(row, q*16u)) = x4;
        }
        __syncthreads();

        // P1: leaf GEMM (M=128) -> HA ; data1 = pairsum(x) -> DB
        gemm_data<4>(D0, 0, 128, HA, (uint32_t)(wm*4), wlf, nt0, BL);
        sumpair(DBf, 0, D0, 0, 64);
        __syncthreads();
        // P2: u1 (M=64) -> U ; data2 -> D0[0:32)
        gemm_data<2>(DBf, 0, 64, Ub, (uint32_t)(wm*2), wlf, nt0, BL);
        sumpair(D0, 0, DBf, 0, 32);
        __syncthreads();
        // P3: nl1 (M=64) -> HB ; data3 -> DB[0:16)
        gemm_nl<2>(HA, Ub, HB, (uint32_t)(wm*2), wnl, nt0, BN);
        sumpair(DBf, 0, D0, 0, 16);
        __syncthreads();
        // P4: u2 (M=32) -> U ; data4 -> DB[16:24)
        gemm_data<1>(D0, 0, 32, Ub, (uint32_t)wm, wlf, nt0, BL);
        sumpair(DBf, 16, DBf, 0, 8);
        __syncthreads();
        // P5: nl2 (M=32) -> HA[0:32)
        gemm_nl<1>(HB, Ub, HA, (uint32_t)wm, wnl, nt0, BN);
        __syncthreads();
        // P6: u3 (M=16) -> U
        if (wm == 0) gemm_data<1>(DBf, 0, 16, Ub, 0, wlf, nt0, BL);
        __syncthreads();
        // P7: nl3 (M=16) -> HB[0:16)
        if (wm == 0) gemm_nl<1>(HA, Ub, HB, 0, wnl, nt0, BN);
        __syncthreads();
        // P8: u4 (M=8 real, 16 padded) -> U
        if (wm == 0) gemm_data<1>(DBf, 16, 8, Ub, 0, wlf, nt0, BL);
        __syncthreads();
        // P9: nl4 -> HCUR ; copy data4 -> DCUR
        if (wm == 0) gemm_nl<1>(HB, Ub, HCUR, 0, wnl, nt0, BN);
        {
            uint32_t row = (uint32_t)(t >> 6), f = (uint32_t)(t & 63);
            *reinterpret_cast<float*>(DCUR + swz(row, f*4u)) =
                *reinterpret_cast<const float*>(DBf + swz(16u + row, f*4u));
        }
        __syncthreads();

        // DFS merges among subtree roots (M=8 padded to 16)
        int nm = __builtin_ctz(s + 1);
        for (int m = 0; m < nm; ++m){
            --sp;
            const char* hl = HSTK + sp*4096;
            ((float*)DCUR)[t] += ((const float*)(DSTK + sp*2048))[t];
            __syncthreads();
            if (wm == 0) gemm_data<1>(DCUR, 0, 8, Ub, 0, wlf, nt0, BL);
            __syncthreads();
            v4f a0 = (v4f){0,0,0,0}, a1 = (v4f){0,0,0,0};
            if (wm == 0){
                #pragma unroll
                for (uint32_t kf = 0; kf < 12; ++kf){
                    const char* src = (kf < 4) ? hl : ((kf < 8) ? (const char*)HCUR
                                                                : (const char*)Ub);
                    v8bf a = ldH(src, kf & 3u);
                    a0 = mfma16(a, wnl[kf][0], a0);
                    a1 = mfma16(a, wnl[kf][1], a1);
                }
            }
            __syncthreads();   // all reads of HCUR done before in-place write
            if (wm == 0){ epi(HCUR, 0, a0, nt0, BN); epi(HCUR, 0, a1, nt0 + 1, BN); }
            __syncthreads();
        }
    }

    // ---- head: z1 = relu(enc@W1+b1); z2 = relu(z1@W2+b2); out = z2@W3+b3 ----
    {
        v8bf w1f[4][2], w2f[4][2];
        #pragma unroll
        for (int kf = 0; kf < 4; ++kf){
            w1f[kf][0] = ldW(W1g, kf*32, n0); w1f[kf][1] = ldW(W1g, kf*32, n0 + 16);
            w2f[kf][0] = ldW(W2g, kf*32, n0); w2f[kf][1] = ldW(W2g, kf*32, n0 + 16);
        }
        if (wm == 0){
            v4f c0 = (v4f){0,0,0,0}, c1 = (v4f){0,0,0,0};
            #pragma unroll
            for (uint32_t kf = 0; kf < 4; ++kf){
                v8bf a = ldH(HCUR, kf);
                c0 = mfma16(a, w1f[kf][0], c0);
                c1 = mfma16(a, w1f[kf][1], c1);
            }
            epi(Ub, 0, c0, nt0, B1L); epi(Ub, 0, c1, nt0 + 1, B1L);
        }
        __syncthreads();
        if (wm == 0){
            v4f c0 = (v4f){0,0,0,0}, c1 = (v4f){0,0,0,0};
            #pragma unroll
            for (uint32_t kf = 0; kf < 4; ++kf){
                v8bf a = ldH(Ub, kf);
                c0 = mfma16(a, w2f[kf][0], c0);
                c1 = mfma16(a, w2f[kf][1], c1);
            }
            epi(HB, 0, c0, nt0, B2L); epi(HB, 0, c1, nt0 + 1, B2L);
        }
        __syncthreads();
        if (t < 64){
            float w3a = W3g[t], w3b = W3g[t + 64], b3v = b3g[0];
            #pragma unroll
            for (int r = 0; r < 8; ++r){
                float za = (float)*reinterpret_cast<const __bf16*>(HB + swz((uint32_t)r, (uint32_t)t*2u));
                float zb = (float)*reinterpret_cast<const __bf16*>(HB + swz((uint32_t)r, (uint32_t)(t + 64)*2u));
                float v = za*w3a + zb*w3b;
                #pragma unroll
                for (int off = 32; off >= 1; off >>= 1) v += __shfl_xor(v, off, 64);
                if (t == 0) Yg[base + r] = v + b3v;
            }
        }
    }
}

extern "C" void kernel_launch(void* const* d_in, const int* in_sizes, int n_in,
                              void* d_out, int out_size, void* d_ws, size_t ws_size,
                              hipStream_t stream){
    const float* x     = (const float*)d_in[0];
    const float* Wleaf = (const float*)d_in[1];
    const float* bleaf = (const float*)d_in[2];
    const float* Wnl   = (const float*)d_in[3];
    const float* bnl   = (const float*)d_in[4];
    const float* W1    = (const float*)d_in[5];
    const float* b1    = (const float*)d_in[6];
    const float* W2    = (const float*)d_in[7];
    const float* b2    = (const float*)d_in[8];
    const float* W3    = (const float*)d_in[9];
    const float* b3    = (const float*)d_in[10];
    float* out = (float*)d_out;

    recnn_kernel<<<B_TOT/BC, NTHR, 0, stream>>>(x, Wleaf, bleaf, Wnl, bnl,
                                                W1, b1, W2, b2, W3, b3, out);
}

// Round 4
// 169.264 us; speedup vs baseline: 2.8348x; 2.8348x over previous
//
#include <hip/hip_runtime.h>
#include <hip/hip_bf16.h>
#include <stdint.h>

// RecNN: B=2048, L=256 leaves, F=64, H=128.
// One workgroup (512 thr, 8 waves) per 8 batch elems. Hybrid subtree-BFS
// (16 leaves level-synchronous, M up to 128) + DFS over 16 subtree roots.
// Each wave owns 16 output cols (nt=wave): persistent weight B-frags = 56
// VGPRs, peak live ~110 < the allocator's 128 target -> no scratch spill
// (round-2/3 post-mortem: 512-thr + 2-nt mapping spilled ~370 MB/dispatch).

#define B_TOT 2048
#define LL    256
#define FF    64
#define HH    128
#define LF    (LL*FF)
#define BC    8
#define NTHR  512
#define SUB   16
#define NSUB  16

typedef __bf16 v8bf __attribute__((ext_vector_type(8)));
typedef float  v4f  __attribute__((ext_vector_type(4)));

// ---- LDS layout (all 2D buffers use 256-byte rows, XOR-swizzled) ----
#define D0_OFF    0        // [128][64] f32   32768  (x / data2 / data-scratch)
#define DB_OFF    32768    // [64][64]  f32   16384  (data1 / data3 / data4@16)
#define HA_OFF    49152    // [128][128]bf16  32768  (h0 / h2)
#define HB_OFF    81920    // [64][128] bf16  16384  (h1 / h3 / z2)
#define U_OFF     98304    // [64][128] bf16  16384  (u / z1)
#define HCUR_OFF  114688   // [16][128] bf16  4096   (subtree/merge root h)
#define DCUR_OFF  118784   // [8][64]   f32   2048   (root data)
#define HSTK_OFF  120832   // 4 x 4096        16384
#define DSTK_OFF  137216   // 4 x 2048        8192
#define BIAS_OFF  145408   // 4 x 512         2048
#define LDS_BYTES 147456

__device__ __forceinline__ uint32_t swz(uint32_t row, uint32_t b){
    return (row*256u + b) ^ ((row & 7u) << 4);
}
__device__ __forceinline__ v4f mfma16(v8bf a, v8bf b, v4f c){
    return __builtin_amdgcn_mfma_f32_16x16x32_bf16(a, b, c, 0, 0, 0);
}

// B-fragment: lane holds col n0+(l&15), k = k0 + 8*(l>>4) + j. W row-major [K][128] f32.
__device__ __forceinline__ v8bf ldW(const float* __restrict__ W, int k0, int n0){
    uint32_t lane = threadIdx.x & 63u;
    int n = n0 + (int)(lane & 15u);
    int k = k0 + (int)((lane >> 4) << 3);
    v8bf r;
    #pragma unroll
    for (int j = 0; j < 8; ++j) r[j] = (__bf16)W[(k + j)*HH + n];
    return r;
}

// A-fragment from 16-row bf16 buffer, row = lane&15 (merge/head GEMMs)
__device__ __forceinline__ v8bf ldH(const char* buf, uint32_t kf){
    uint32_t lane = threadIdx.x & 63u;
    uint32_t kb = (kf*32u + ((lane >> 4) << 3)) * 2u;
    return *reinterpret_cast<const v8bf*>(buf + swz(lane & 15u, kb));
}

// A-fragment for subtree nl GEMM (node-major rows): tile row r -> node 2mt+(r>=8),
// children rows 32mt+16*(r>=8)+8*sec+(r&7) in hprev; u row 16mt+r.
__device__ __forceinline__ v8bf ldA_nl(const char* hprev, const char* ub, uint32_t mt, uint32_t kf){
    uint32_t lane = threadIdx.x & 63u, r = lane & 15u;
    uint32_t kb = ((kf & 3u)*32u + ((lane >> 4) << 3)) * 2u;
    uint32_t sec = kf >> 2;
    if (sec < 2u){
        uint32_t row = mt*32u + ((r >> 3) << 4) + sec*8u + (r & 7u);
        return *reinterpret_cast<const v8bf*>(hprev + swz(row, kb));
    }
    return *reinterpret_cast<const v8bf*>(ub + swz(mt*16u + r, kb));
}

// A-fragment from f32 data buffer (K=64), on-the-fly bf16 convert; rows >= realrows -> 0
__device__ __forceinline__ v8bf ldA_f32(const char* dbuf, uint32_t rowbase, uint32_t mt,
                                        uint32_t kf, uint32_t realrows){
    uint32_t lane = threadIdx.x & 63u, r = lane & 15u;
    uint32_t row = mt*16u + r;
    v8bf o;
    if (row >= realrows){
        #pragma unroll
        for (int j = 0; j < 8; ++j) o[j] = (__bf16)0.0f;
        return o;
    }
    uint32_t kb = kf*128u + ((lane >> 4) << 5);
    v4f lo = *reinterpret_cast<const v4f*>(dbuf + swz(rowbase + row, kb));
    v4f hi = *reinterpret_cast<const v4f*>(dbuf + swz(rowbase + row, kb + 16u));
    #pragma unroll
    for (int j = 0; j < 4; ++j){ o[j] = (__bf16)lo[j]; o[j+4] = (__bf16)hi[j]; }
    return o;
}

// Epilogue: D elem r -> [row0+(l>>4)*4+r][16*nt+(l&15)]; relu(acc+bias) -> bf16 swz LDS
__device__ __forceinline__ void epi(char* dst, uint32_t row0, v4f acc, int nt, const float* bias){
    uint32_t lane = threadIdx.x & 63u;
    uint32_t col = (uint32_t)nt*16u + (lane & 15u);
    float bv = bias[col];
    uint32_t r0 = row0 + ((lane >> 4) << 2);
    #pragma unroll
    for (int r = 0; r < 4; ++r){
        float v = fmaxf(acc[r] + bv, 0.f);
        *reinterpret_cast<__bf16*>(dst + swz(r0 + r, col*2u)) = (__bf16)v;
    }
}

// relu(data @ Wleaf + bias) for MTN 16-row tiles starting at tile mtB (all waves, own nt)
template<int MTN>
__device__ __forceinline__ void gemm_data(const char* dbuf, uint32_t rowbase, uint32_t realrows,
                                          char* dst, uint32_t mtB, const v8bf (&wlf)[2],
                                          int nt, const float* bias){
    v4f acc[MTN];
    #pragma unroll
    for (int i = 0; i < MTN; ++i) acc[i] = (v4f){0,0,0,0};
    #pragma unroll
    for (uint32_t kf = 0; kf < 2; ++kf){
        v8bf a[MTN];
        #pragma unroll
        for (int i = 0; i < MTN; ++i) a[i] = ldA_f32(dbuf, rowbase, mtB + i, kf, realrows);
        #pragma unroll
        for (int i = 0; i < MTN; ++i) acc[i] = mfma16(a[i], wlf[kf], acc[i]);
    }
    #pragma unroll
    for (int i = 0; i < MTN; ++i) epi(dst, (mtB + i)*16u, acc[i], nt, bias);
}

// relu([h_even|h_odd|u] @ Wnl + bias), node-major (all waves, own nt)
template<int MTN>
__device__ __forceinline__ void gemm_nl(const char* hprev, const char* ub, char* dst, uint32_t mtB,
                                        const v8bf (&wnl)[12], int nt, const float* bias){
    v4f acc[MTN];
    #pragma unroll
    for (int i = 0; i < MTN; ++i) acc[i] = (v4f){0,0,0,0};
    #pragma unroll
    for (uint32_t kf = 0; kf < 12; ++kf){
        v8bf a[MTN];
        #pragma unroll
        for (int i = 0; i < MTN; ++i) a[i] = ldA_nl(hprev, ub, mtB + i, kf);
        #pragma unroll
        for (int i = 0; i < MTN; ++i) acc[i] = mfma16(a[i], wnl[kf], acc[i]);
    }
    #pragma unroll
    for (int i = 0; i < MTN; ++i) epi(dst, (mtB + i)*16u, acc[i], nt, bias);
}

// data_next[n*8+b] = data[16n+b] + data[16n+8+b], elementwise over swizzled f32 rows
__device__ __forceinline__ void sumpair(char* dstbuf, uint32_t dRow0, const char* srcbuf,
                                        uint32_t sRow0, int nrows){
    int total = nrows * 64;
    for (int idx = threadIdx.x; idx < total; idx += NTHR){
        uint32_t row = (uint32_t)(idx >> 6), f = (uint32_t)(idx & 63);
        uint32_t n = row >> 3, b = row & 7u;
        float x0 = *reinterpret_cast<const float*>(srcbuf + swz(sRow0 + n*16u + b,      f*4u));
        float x1 = *reinterpret_cast<const float*>(srcbuf + swz(sRow0 + n*16u + 8u + b, f*4u));
        *reinterpret_cast<float*>(dstbuf + swz(dRow0 + row, f*4u)) = x0 + x1;
    }
}

__global__ __launch_bounds__(NTHR)
__attribute__((amdgpu_waves_per_eu(2, 2)))
void recnn_kernel(const float* __restrict__ Xg,
                  const float* __restrict__ Wleaf, const float* __restrict__ bleaf,
                  const float* __restrict__ Wnl,   const float* __restrict__ bnl,
                  const float* __restrict__ W1g,   const float* __restrict__ b1g,
                  const float* __restrict__ W2g,   const float* __restrict__ b2g,
                  const float* __restrict__ W3g,   const float* __restrict__ b3g,
                  float* __restrict__ Yg)
{
    __shared__ __align__(16) char lds[LDS_BYTES];
    const int t    = threadIdx.x;
    const int wave = t >> 6;
    const int base = blockIdx.x * BC;

    char*  D0   = lds + D0_OFF;
    char*  DBf  = lds + DB_OFF;
    char*  HA   = lds + HA_OFF;
    char*  HB   = lds + HB_OFF;
    char*  Ub   = lds + U_OFF;
    char*  HCUR = lds + HCUR_OFF;
    char*  DCUR = lds + DCUR_OFF;
    char*  HSTK = lds + HSTK_OFF;
    char*  DSTK = lds + DSTK_OFF;
    float* BL   = (float*)(lds + BIAS_OFF);
    float* BN   = BL + 128;
    float* B1L  = BL + 256;
    float* B2L  = BL + 384;

    if (t < 128){
        BL[t]  = bleaf[t];
        BN[t]  = bnl[t];
        B1L[t] = b1g[t];
        B2L[t] = b2g[t];
    }

    // Persistent weight fragments: wave owns output cols [16*wave, 16*wave+16)
    const int n0 = wave << 4;
    const int nt = wave;
    v8bf wlf[2], wnl[12];
    #pragma unroll
    for (int kf = 0; kf < 2; ++kf)  wlf[kf] = ldW(Wleaf, kf*32, n0);
    #pragma unroll
    for (int kf = 0; kf < 12; ++kf) wnl[kf] = ldW(Wnl, kf*32, n0);

    int sp = 0;
    for (int s = 0; s < NSUB; ++s){
        // push previous root, stage x for this subtree -> D0 (f32 swz)
        if (s > 0){
            ((uint2*)(HSTK + sp*4096))[t]     = ((const uint2*)HCUR)[t];
            ((uint32_t*)(DSTK + sp*2048))[t]  = ((const uint32_t*)DCUR)[t];
            ++sp;
        }
        #pragma unroll
        for (int k = 0; k < 4; ++k){
            int idx = t + k*NTHR;                       // 0..2047
            uint32_t row = (uint32_t)(idx >> 4), q = (uint32_t)(idx & 15);
            int li = (int)(row >> 3), bb = (int)(row & 7u);
            v4f x4 = *reinterpret_cast<const v4f*>(
                Xg + (size_t)(base + bb)*LF + (size_t)(s*SUB + li)*FF + q*4);
            *reinterpret_cast<v4f*>(D0 + swz(row, q*16u)) = x4;
        }
        __syncthreads();

        // P1: leaf GEMM (M=128) -> HA ; data1 = pairsum(x) -> DB
        gemm_data<4>(D0, 0, 128, HA, 0, wlf, nt, BL);
        gemm_data<4>(D0, 0, 128, HA, 4, wlf, nt, BL);
        sumpair(DBf, 0, D0, 0, 64);
        __syncthreads();
        // P2: u1 (M=64) -> U ; data2 -> D0[0:32)
        gemm_data<4>(DBf, 0, 64, Ub, 0, wlf, nt, BL);
        sumpair(D0, 0, DBf, 0, 32);
        __syncthreads();
        // P3: nl1 (M=64) -> HB ; data3 -> DB[0:16)
        gemm_nl<4>(HA, Ub, HB, 0, wnl, nt, BN);
        sumpair(DBf, 0, D0, 0, 16);
        __syncthreads();
        // P4: u2 (M=32) -> U ; data4 -> DB[16:24)
        gemm_data<2>(D0, 0, 32, Ub, 0, wlf, nt, BL);
        sumpair(DBf, 16, DBf, 0, 8);
        __syncthreads();
        // P5: nl2 (M=32) -> HA[0:32)
        gemm_nl<2>(HB, Ub, HA, 0, wnl, nt, BN);
        __syncthreads();
        // P6: u3 (M=16) -> U
        gemm_data<1>(DBf, 0, 16, Ub, 0, wlf, nt, BL);
        __syncthreads();
        // P7: nl3 (M=16) -> HB[0:16)
        gemm_nl<1>(HA, Ub, HB, 0, wnl, nt, BN);
        __syncthreads();
        // P8: u4 (M=8 real, 16 padded) -> U
        gemm_data<1>(DBf, 16, 8, Ub, 0, wlf, nt, BL);
        __syncthreads();
        // P9: nl4 -> HCUR ; copy data4 -> DCUR
        gemm_nl<1>(HB, Ub, HCUR, 0, wnl, nt, BN);
        {
            uint32_t row = (uint32_t)(t >> 6), f = (uint32_t)(t & 63);
            *reinterpret_cast<float*>(DCUR + swz(row, f*4u)) =
                *reinterpret_cast<const float*>(DBf + swz(16u + row, f*4u));
        }
        __syncthreads();

        // DFS merges among subtree roots (M=8 padded to 16)
        int nm = __builtin_ctz(s + 1);
        for (int m = 0; m < nm; ++m){
            --sp;
            const char* hl = HSTK + sp*4096;
            ((float*)DCUR)[t] += ((const float*)(DSTK + sp*2048))[t];
            __syncthreads();
            gemm_data<1>(DCUR, 0, 8, Ub, 0, wlf, nt, BL);
            __syncthreads();
            v4f a0 = (v4f){0,0,0,0};
            #pragma unroll
            for (uint32_t kf = 0; kf < 12; ++kf){
                const char* src = (kf < 4) ? hl : ((kf < 8) ? (const char*)HCUR
                                                            : (const char*)Ub);
                v8bf a = ldH(src, kf & 3u);
                a0 = mfma16(a, wnl[kf], a0);
            }
            __syncthreads();   // all reads of HCUR done before in-place write
            epi(HCUR, 0, a0, nt, BN);
            __syncthreads();
        }
    }

    // ---- head: z1 = relu(enc@W1+b1); z2 = relu(z1@W2+b2); out = z2@W3+b3 ----
    {
        v8bf w1f[4], w2f[4];
        #pragma unroll
        for (int kf = 0; kf < 4; ++kf){
            w1f[kf] = ldW(W1g, kf*32, n0);
            w2f[kf] = ldW(W2g, kf*32, n0);
        }
        {
            v4f c0 = (v4f){0,0,0,0};
            #pragma unroll
            for (uint32_t kf = 0; kf < 4; ++kf) c0 = mfma16(ldH(HCUR, kf), w1f[kf], c0);
            epi(Ub, 0, c0, nt, B1L);
        }
        __syncthreads();
        {
            v4f c0 = (v4f){0,0,0,0};
            #pragma unroll
            for (uint32_t kf = 0; kf < 4; ++kf) c0 = mfma16(ldH(Ub, kf), w2f[kf], c0);
            epi(HB, 0, c0, nt, B2L);
        }
        __syncthreads();
        if (t < 64){
            float w3a = W3g[t], w3b = W3g[t + 64], b3v = b3g[0];
            #pragma unroll
            for (int r = 0; r < 8; ++r){
                float za = (float)*reinterpret_cast<const __bf16*>(HB + swz((uint32_t)r, (uint32_t)t*2u));
                float zb = (float)*reinterpret_cast<const __bf16*>(HB + swz((uint32_t)r, (uint32_t)(t + 64)*2u));
                float v = za*w3a + zb*w3b;
                #pragma unroll
                for (int off = 32; off >= 1; off >>= 1) v += __shfl_xor(v, off, 64);
                if (t == 0) Yg[base + r] = v + b3v;
            }
        }
    }
}

extern "C" void kernel_launch(void* const* d_in, const int* in_sizes, int n_in,
                              void* d_out, int out_size, void* d_ws, size_t ws_size,
                              hipStream_t stream){
    const float* x     = (const float*)d_in[0];
    const float* Wleaf = (const float*)d_in[1];
    const float* bleaf = (const float*)d_in[2];
    const float* Wnl   = (const float*)d_in[3];
    const float* bnl   = (const float*)d_in[4];
    const float* W1    = (const float*)d_in[5];
    const float* b1    = (const float*)d_in[6];
    const float* W2    = (const float*)d_in[7];
    const float* b2    = (const float*)d_in[8];
    const float* W3    = (const float*)d_in[9];
    const float* b3    = (const float*)d_in[10];
    float* out = (float*)d_out;

    recnn_kernel<<<B_TOT/BC, NTHR, 0, stream>>>(x, Wleaf, bleaf, Wnl, bnl,
                                                W1, b1, W2, b2, W3, b3, out);
}